// Round 1
// baseline (591.693 us; speedup 1.0000x reference)
//
#include <hip/hip_runtime.h>

// ---------------------------------------------------------------------------
// DWTFeatureModel: pool(2x2) -> 4-level db4 DWT (len 128 -> 154) -> einsum.
// DWT + einsum folded into one effective weight Weff[b][f][k], k = s*16+h*4+w.
// ---------------------------------------------------------------------------

#define NBINS 4
#define NFEAT 48
#define DWT_LEN 154

// H0R = DEC_LO reversed, H1R = DEC_HI reversed (matches jax conv = correlation)
__device__ __constant__ float c_h0r[8] = {
    0.23037781330885523f,  0.7148465705525415f,   0.6308807679295904f,
   -0.02798376941698385f, -0.18703481171888114f,  0.030841381835986965f,
    0.032883011666982945f, -0.010597401784997278f };
__device__ __constant__ float c_h1r[8] = {
   -0.010597401784997278f, -0.032883011666982945f, 0.030841381835986965f,
    0.18703481171888114f,  -0.02798376941698385f, -0.6308807679295904f,
    0.7148465705525415f,   -0.23037781330885523f };

// Build D[154][128]: column s = dwt_concat(e_s). One thread per column.
__global__ void build_dwt_matrix(float* __restrict__ D) {
  int s = threadIdx.x;
  if (s >= 128) return;
  float work[128];
  for (int i = 0; i < 128; ++i) work[i] = 0.f;
  work[s] = 1.f;
  float tmp[67];
  int N = 128;
  const int HI_OFF[4] = {14, 81, 118, 140}; // lo occupies rows 0..13
  for (int lev = 0; lev < 4; ++lev) {
    int out = (N + 7) >> 1;
    int p  = 2 * (out - 1) - N + 8;
    int pl = p >> 1;
    for (int k = 0; k < out; ++k) {
      float lo = 0.f, hi = 0.f;
      #pragma unroll
      for (int l = 0; l < 8; ++l) {
        int idx = 2 * k + l - pl;
        idx = idx < 0 ? -idx : idx;            // reflect (no edge repeat)
        idx = idx >= N ? 2 * N - 2 - idx : idx;
        float v = work[idx];
        lo += c_h0r[l] * v;
        hi += c_h1r[l] * v;
      }
      tmp[k] = lo;
      D[(HI_OFF[lev] + k) * 128 + s] = hi;
    }
    for (int k = 0; k < out; ++k) work[k] = tmp[k];
    N = out;
  }
  for (int k = 0; k < 14; ++k) D[k * 128 + s] = work[k];
}

// Weff[bf][s*16+hw] = sum_t conv_w[bf][t][hw] * D[t][s].  192 blocks x 256 thr.
__global__ void build_weff(const float* __restrict__ conv_w,
                           const float* __restrict__ D,
                           float* __restrict__ Weff) {
  int bf = blockIdx.x; // 0..191
  __shared__ float cw[DWT_LEN * 16];
  for (int i = threadIdx.x; i < DWT_LEN * 16; i += blockDim.x)
    cw[i] = conv_w[(size_t)bf * (DWT_LEN * 16) + i];
  __syncthreads();
  for (int idx = threadIdx.x; idx < 2048; idx += blockDim.x) {
    int s = idx & 127;        // consecutive lanes -> consecutive s: D coalesced
    int hw = idx >> 7;
    float acc = 0.f;
    for (int t = 0; t < DWT_LEN; ++t)
      acc += cw[t * 16 + hw] * D[t * 128 + s];
    Weff[(size_t)bf * 2048 + s * 16 + hw] = acc;
  }
}

// Main fused kernel: one wave handles 4 consecutive n for one bin b.
// Pooled signal lives entirely in registers (pa[4][8] float4 = k 0..2047).
__global__ __launch_bounds__(256, 2)
void dwt_feat_main(const float* __restrict__ x,
                   const float* __restrict__ Weff,
                   const float* __restrict__ conv_b,
                   float* __restrict__ out, int n_total) {
  int lane = threadIdx.x & 63;
  int wid  = blockIdx.x * 4 + (threadIdx.x >> 6); // global wave id, 0..n-1
  int b  = wid & 3;
  int n0 = (wid >> 2) * 4;
  if (n0 >= n_total) return;

  // ---- phase 1: pool 2x2 in registers. lane's float4 = k-index pass*64+lane
  float4 pa[4][8];
  #pragma unroll
  for (int nn = 0; nn < 4; ++nn) {
    const float4* xs =
        (const float4*)(x + (size_t)(n0 + nn) * 32768 + (size_t)b * 8192);
    #pragma unroll
    for (int pass = 0; pass < 8; ++pass) {
      int fi = pass * 256 + lane * 4; // 64 contiguous bytes per lane
      float4 a0 = xs[fi + 0], a1 = xs[fi + 1];
      float4 b0 = xs[fi + 2], b1 = xs[fi + 3];
      float4 pv;
      pv.x = fmaxf(fmaxf(a0.x, a0.y), fmaxf(b0.x, b0.y));
      pv.y = fmaxf(fmaxf(a0.z, a0.w), fmaxf(b0.z, b0.w));
      pv.z = fmaxf(fmaxf(a1.x, a1.y), fmaxf(b1.x, b1.y));
      pv.w = fmaxf(fmaxf(a1.z, a1.w), fmaxf(b1.z, b1.w));
      pa[nn][pass] = pv;
    }
  }

  // ---- phase 2: 48 features, Weff rows read coalesced (L2-resident, 1.5 MB)
  const float4* W4 = (const float4*)(Weff + (size_t)b * NFEAT * 2048);
  const float* bias = conv_b + b * NFEAT;
  for (int f = 0; f < NFEAT; ++f) {
    float acc0 = 0.f, acc1 = 0.f, acc2 = 0.f, acc3 = 0.f;
    #pragma unroll
    for (int pass = 0; pass < 8; ++pass) {
      float4 w = W4[f * 512 + pass * 64 + lane];
      float4 p0 = pa[0][pass], p1 = pa[1][pass], p2 = pa[2][pass], p3 = pa[3][pass];
      acc0 += p0.x * w.x + p0.y * w.y + p0.z * w.z + p0.w * w.w;
      acc1 += p1.x * w.x + p1.y * w.y + p1.z * w.z + p1.w * w.w;
      acc2 += p2.x * w.x + p2.y * w.y + p2.z * w.z + p2.w * w.w;
      acc3 += p3.x * w.x + p3.y * w.y + p3.z * w.z + p3.w * w.w;
    }
    #pragma unroll
    for (int m = 32; m >= 1; m >>= 1) {
      acc0 += __shfl_xor(acc0, m, 64);
      acc1 += __shfl_xor(acc1, m, 64);
      acc2 += __shfl_xor(acc2, m, 64);
      acc3 += __shfl_xor(acc3, m, 64);
    }
    if (lane < 4) {
      float v = lane == 0 ? acc0 : lane == 1 ? acc1 : lane == 2 ? acc2 : acc3;
      v += bias[f];
      v = v > 0.f ? v : 0.02f * v;
      out[(size_t)(n0 + lane) * (NBINS * NFEAT) + b * NFEAT + f] = v;
    }
  }
}

extern "C" void kernel_launch(void* const* d_in, const int* in_sizes, int n_in,
                              void* d_out, int out_size, void* d_ws, size_t ws_size,
                              hipStream_t stream) {
  const float* x      = (const float*)d_in[0]; // (n,1,512,8,8)
  const float* conv_w = (const float*)d_in[1]; // (4,48,154,4,4)
  const float* conv_b = (const float*)d_in[2]; // (4,48)
  float* out = (float*)d_out;

  float* D    = (float*)d_ws;            // 154*128 floats = 77 KB
  float* Weff = (float*)d_ws + 32768;    // at 128 KB offset; 4*48*2048 floats = 1.5 MB

  int n = in_sizes[0] / 32768; // 2048

  build_dwt_matrix<<<1, 128, 0, stream>>>(D);
  build_weff<<<NBINS * NFEAT, 256, 0, stream>>>(conv_w, D, Weff);
  // one wave per (4-n group, bin): n waves total, 4 waves (256 thr) per block
  dwt_feat_main<<<(n + 3) / 4, 256, 0, stream>>>(x, Weff, conv_b, out, n);
}

// Round 2
// 495.142 us; speedup vs baseline: 1.1950x; 1.1950x over previous
//
#include <hip/hip_runtime.h>

// ---------------------------------------------------------------------------
// DWTFeatureModel: pool(2x2) -> 4-level db4 DWT (len 128 -> 154) -> einsum.
// DWT + einsum folded into one effective weight Weff[b][f][k], k = s*16+h*4+w.
// Main kernel: block = (4 n, bin b); 4 waves each own a k-quarter; LDS combine.
// ---------------------------------------------------------------------------

#define NBINS 4
#define NFEAT 48
#define DWT_LEN 154

// H0R = DEC_LO reversed, H1R = DEC_HI reversed (matches jax conv = correlation)
__device__ __constant__ float c_h0r[8] = {
    0.23037781330885523f,  0.7148465705525415f,   0.6308807679295904f,
   -0.02798376941698385f, -0.18703481171888114f,  0.030841381835986965f,
    0.032883011666982945f, -0.010597401784997278f };
__device__ __constant__ float c_h1r[8] = {
   -0.010597401784997278f, -0.032883011666982945f, 0.030841381835986965f,
    0.18703481171888114f,  -0.02798376941698385f, -0.6308807679295904f,
    0.7148465705525415f,   -0.23037781330885523f };

// Build D[154][128]: column s = dwt_concat(e_s). 2 blocks x 64 columns.
// Work arrays live in LDS (uniform dynamic index would hit scratch in regs).
__global__ void build_dwt_matrix(float* __restrict__ D) {
  __shared__ float work[128 * 64];
  __shared__ float tmp[67 * 64];
  int ls = threadIdx.x;            // 0..63
  int s  = blockIdx.x * 64 + ls;   // global column
  for (int i = 0; i < 128; ++i) work[i * 64 + ls] = (i == s) ? 1.f : 0.f;
  int N = 128;
  const int HI_OFF[4] = {14, 81, 118, 140}; // lo occupies rows 0..13
  for (int lev = 0; lev < 4; ++lev) {
    int out = (N + 7) >> 1;
    int p  = 2 * (out - 1) - N + 8;
    int pl = p >> 1;
    for (int k = 0; k < out; ++k) {
      float lo = 0.f, hi = 0.f;
      #pragma unroll
      for (int l = 0; l < 8; ++l) {
        int idx = 2 * k + l - pl;
        idx = idx < 0 ? -idx : idx;            // reflect (no edge repeat)
        idx = idx >= N ? 2 * N - 2 - idx : idx;
        float v = work[idx * 64 + ls];
        lo += c_h0r[l] * v;
        hi += c_h1r[l] * v;
      }
      tmp[k * 64 + ls] = lo;
      D[(HI_OFF[lev] + k) * 128 + s] = hi;
    }
    for (int k = 0; k < out; ++k) work[k * 64 + ls] = tmp[k * 64 + ls];
    N = out;
  }
  for (int k = 0; k < 14; ++k) D[k * 128 + s] = work[k * 64 + ls];
}

// Weff[bf][s*16+hw] = sum_t conv_w[bf][t][hw] * D[t][s].  192 blocks x 256 thr.
// Each thread owns s = tid&127, hw = (tid>>7)+2j (j=0..7): one coalesced D load
// per t feeds 8 FMAs (ILP-8).
__global__ void build_weff(const float* __restrict__ conv_w,
                           const float* __restrict__ D,
                           float* __restrict__ Weff) {
  int bf = blockIdx.x; // 0..191
  __shared__ float cw[DWT_LEN * 16];
  for (int i = threadIdx.x; i < DWT_LEN * 16; i += blockDim.x)
    cw[i] = conv_w[(size_t)bf * (DWT_LEN * 16) + i];
  __syncthreads();
  int s  = threadIdx.x & 127;
  int h0 = threadIdx.x >> 7; // 0 or 1
  float acc[8] = {0.f, 0.f, 0.f, 0.f, 0.f, 0.f, 0.f, 0.f};
  #pragma unroll 4
  for (int t = 0; t < DWT_LEN; ++t) {
    float d = D[t * 128 + s];
    #pragma unroll
    for (int j = 0; j < 8; ++j) acc[j] += cw[t * 16 + h0 + 2 * j] * d;
  }
  #pragma unroll
  for (int j = 0; j < 8; ++j) {
    int hw = h0 + 2 * j;
    Weff[(size_t)bf * 2048 + s * 16 + hw] = acc[j];
  }
}

// Main fused kernel: block = (4 consecutive n, bin b), 4 waves = 4 k-quarters.
// Pooled k-quarter lives in registers (pa[4][2] float4 = k-range kq*512..+512).
__global__ __launch_bounds__(256, 4)
void dwt_feat_main(const float* __restrict__ x,
                   const float* __restrict__ Weff,
                   const float* __restrict__ conv_b,
                   float* __restrict__ out, int n_total) {
  __shared__ float part[4][NFEAT][4]; // [kq][f][nn]
  int lane = threadIdx.x & 63;
  int kq   = threadIdx.x >> 6;   // k-quarter owned by this wave
  int b    = blockIdx.x & 3;
  int n0   = (blockIdx.x >> 2) * 4;
  if (n0 >= n_total) return;

  // ---- phase 1: pool 2x2 in registers. pa[nn][pp] = pooled float4 at
  //      k-float4-index (kq*2+pp)*64 + lane  (k = s*16+h*4+w flat index).
  float4 pa[4][2];
  #pragma unroll
  for (int nn = 0; nn < 4; ++nn) {
    const float4* xs =
        (const float4*)(x + (size_t)(n0 + nn) * 32768 + (size_t)b * 8192);
    #pragma unroll
    for (int pp = 0; pp < 2; ++pp) {
      int fi = (kq * 2 + pp) * 256 + lane * 4; // 64 contiguous bytes per lane
      float4 a0 = xs[fi + 0], a1 = xs[fi + 1];
      float4 b0 = xs[fi + 2], b1 = xs[fi + 3];
      float4 pv;
      pv.x = fmaxf(fmaxf(a0.x, a0.y), fmaxf(b0.x, b0.y));
      pv.y = fmaxf(fmaxf(a0.z, a0.w), fmaxf(b0.z, b0.w));
      pv.z = fmaxf(fmaxf(a1.x, a1.y), fmaxf(b1.x, b1.y));
      pv.w = fmaxf(fmaxf(a1.z, a1.w), fmaxf(b1.z, b1.w));
      pa[nn][pp] = pv;
    }
  }

  // ---- phase 2: 48 features; each wave contracts its k-quarter against Weff
  //      (L2-resident, 1.5 MB total; each W line read once per block).
  const float4* W4 = (const float4*)(Weff + (size_t)b * NFEAT * 2048);
  for (int f = 0; f < NFEAT; ++f) {
    float acc0 = 0.f, acc1 = 0.f, acc2 = 0.f, acc3 = 0.f;
    #pragma unroll
    for (int pp = 0; pp < 2; ++pp) {
      float4 w = W4[f * 512 + (kq * 2 + pp) * 64 + lane];
      float4 p0 = pa[0][pp], p1 = pa[1][pp], p2 = pa[2][pp], p3 = pa[3][pp];
      acc0 += p0.x * w.x + p0.y * w.y + p0.z * w.z + p0.w * w.w;
      acc1 += p1.x * w.x + p1.y * w.y + p1.z * w.z + p1.w * w.w;
      acc2 += p2.x * w.x + p2.y * w.y + p2.z * w.z + p2.w * w.w;
      acc3 += p3.x * w.x + p3.y * w.y + p3.z * w.z + p3.w * w.w;
    }
    #pragma unroll
    for (int m = 32; m >= 1; m >>= 1) {
      acc0 += __shfl_xor(acc0, m, 64);
      acc1 += __shfl_xor(acc1, m, 64);
      acc2 += __shfl_xor(acc2, m, 64);
      acc3 += __shfl_xor(acc3, m, 64);
    }
    if (lane < 4) {
      float v = lane == 0 ? acc0 : lane == 1 ? acc1 : lane == 2 ? acc2 : acc3;
      part[kq][f][lane] = v;
    }
  }
  __syncthreads();

  // ---- phase 3: combine k-quarters, bias + leaky-relu, write.
  int t = threadIdx.x;
  if (t < NFEAT * 4) {
    int f  = t % NFEAT;  // consecutive t -> consecutive f: coalesced runs
    int nn = t / NFEAT;
    float v = part[0][f][nn] + part[1][f][nn] + part[2][f][nn] + part[3][f][nn];
    v += conv_b[b * NFEAT + f];
    v = v > 0.f ? v : 0.02f * v;
    out[(size_t)(n0 + nn) * (NBINS * NFEAT) + b * NFEAT + f] = v;
  }
}

extern "C" void kernel_launch(void* const* d_in, const int* in_sizes, int n_in,
                              void* d_out, int out_size, void* d_ws, size_t ws_size,
                              hipStream_t stream) {
  const float* x      = (const float*)d_in[0]; // (n,1,512,8,8)
  const float* conv_w = (const float*)d_in[1]; // (4,48,154,4,4)
  const float* conv_b = (const float*)d_in[2]; // (4,48)
  float* out = (float*)d_out;

  float* D    = (float*)d_ws;            // 154*128 floats = 77 KB
  float* Weff = (float*)d_ws + 32768;    // at 128 KB offset; 4*48*2048 floats = 1.5 MB

  int n = in_sizes[0] / 32768; // 2048

  build_dwt_matrix<<<2, 64, 0, stream>>>(D);
  build_weff<<<NBINS * NFEAT, 256, 0, stream>>>(conv_w, D, Weff);
  // block = (4-n group, bin): 4 waves = 4 k-quarters
  dwt_feat_main<<<(n / 4) * NBINS, 256, 0, stream>>>(x, Weff, conv_b, out, n);
}